// Round 2
// baseline (1338.027 us; speedup 1.0000x reference)
//
#include <hip/hip_runtime.h>

#define FILTER_LEN 8
#define HIDDEN 32
#define CHANNEL 512
#define BATCH 256
#define SEQLEN 2048

// ---------------------------------------------------------------------------
// Kernel A: stat[b,c] = max over L of x[b,c,:]. 131072 rows of 2048 fp32.
// One wave (64 lanes) per row; 4 waves per block. Each lane: 8 x float4 loads
// (1 KB per wave per instruction, perfectly coalesced).
// ---------------------------------------------------------------------------
__global__ __launch_bounds__(256) void rowmax_kernel(const float4* __restrict__ x,
                                                     float* __restrict__ stat) {
    const int wave = threadIdx.x >> 6;
    const int lane = threadIdx.x & 63;
    const long long row = (long long)blockIdx.x * 4 + wave;
    const float4* rp = x + row * (SEQLEN / 4);   // 512 float4 per row

    float m = -3.402823466e38f;
    #pragma unroll
    for (int k = 0; k < 8; ++k) {
        float4 v = rp[k * 64 + lane];
        m = fmaxf(m, fmaxf(fmaxf(v.x, v.y), fmaxf(v.z, v.w)));
    }
    #pragma unroll
    for (int off = 32; off > 0; off >>= 1)
        m = fmaxf(m, __shfl_down(m, off, 64));
    if (lane == 0) stat[row] = m;
}

// ---------------------------------------------------------------------------
// Kernel B: per-sample MLP. One 64-thread block (one wave) per sample b.
//   h1 = relu(stat_b @ W1.T + b1)   (512 -> 32)
//   h2 = relu(h1 @ W2.T + b2)       (32 -> 32)
//   f  = h2 @ W3.T + b3             (32 -> 16)
// W1 staged transposed in LDS in TWO 256-channel passes (32 KB buffer, well
// under the 64 KB static-LDS limit). Add-swizzle idx(c,j)=c*32+((j+c)&31)
// makes both staging writes and dot reads bank-conflict-free.
// ---------------------------------------------------------------------------
__global__ __launch_bounds__(64) void mlp_kernel(const float* __restrict__ stat,
                                                 const float* __restrict__ W1,
                                                 const float* __restrict__ b1,
                                                 const float* __restrict__ W2,
                                                 const float* __restrict__ b2,
                                                 const float* __restrict__ W3,
                                                 const float* __restrict__ b3,
                                                 float* __restrict__ out,
                                                 float* __restrict__ filt) {
    __shared__ float s_w[256 * 32];     // 32 KB: one 256-channel slab of W1^T, swizzled
    __shared__ float s_stat[CHANNEL];
    __shared__ float s_h1[HIDDEN];
    __shared__ float s_h2[HIDDEN];

    const int b = blockIdx.x;
    const int t = threadIdx.x;
    const int j = t & 31;
    const int half = t >> 5;

    for (int c = t; c < CHANNEL; c += 64) s_stat[c] = stat[b * CHANNEL + c];

    float acc = 0.f;
    #pragma unroll
    for (int pass = 0; pass < 2; ++pass) {
        __syncthreads();   // previous pass's readers done (also covers s_stat staging)
        // stage W1[:, pass*256 : pass*256+256] transposed+swizzled
        for (int i = t; i < HIDDEN * 256; i += 64) {
            int jj = i >> 8;        // output index 0..31
            int cc = i & 255;       // channel within slab
            s_w[cc * 32 + ((jj + cc) & 31)] = W1[jj * CHANNEL + pass * 256 + cc];
        }
        __syncthreads();
        const int cbase = half * 128;
        #pragma unroll 8
        for (int k = 0; k < 128; ++k) {
            int cc = cbase + k;
            acc += s_stat[pass * 256 + cc] * s_w[cc * 32 + ((j + cc) & 31)];
        }
    }
    acc += __shfl_xor(acc, 32, 64);   // combine the two channel-halves

    if (t < HIDDEN) s_h1[t] = fmaxf(acc + b1[t], 0.f);
    __syncthreads();

    if (t < HIDDEN) {
        float a2 = b2[t];
        #pragma unroll
        for (int c = 0; c < HIDDEN; ++c) a2 += s_h1[c] * W2[t * HIDDEN + c];
        s_h2[t] = fmaxf(a2, 0.f);
    }
    __syncthreads();

    if (t < 2 * FILTER_LEN) {
        float a3 = b3[t];
        #pragma unroll
        for (int c = 0; c < HIDDEN; ++c) a3 += s_h2[c] * W3[t * HIDDEN + c];
        filt[b * 16 + t] = a3;
        int idx = (t < FILTER_LEN)
                      ? (b * FILTER_LEN + t)                              // lo_f
                      : (BATCH * FILTER_LEN + b * FILTER_LEN + (t - 8));  // hi_f
        out[idx] = a3;
    }
}

// ---------------------------------------------------------------------------
// Kernel C: ortho loss. One block, one thread per sample; block-reduce sum.
// ---------------------------------------------------------------------------
__global__ __launch_bounds__(256) void loss_kernel(const float* __restrict__ filt,
                                                   float* __restrict__ out) {
    const int b = threadIdx.x;
    float lo[8], hi[8];
    #pragma unroll
    for (int i = 0; i < 8; ++i) {
        lo[i] = filt[b * 16 + i];
        hi[i] = filt[b * 16 + 8 + i];
    }
    float sl = 0.f, sh = 0.f;
    #pragma unroll
    for (int i = 0; i < 8; ++i) { sl += lo[i] * lo[i]; sh += hi[i] * hi[i]; }
    const float inl = 1.f / sqrtf(sl);
    const float inh = 1.f / sqrtf(sh);
    float Ln[8], Hn[8];
    #pragma unroll
    for (int i = 0; i < 8; ++i) { Ln[i] = lo[i] * inl; Hn[i] = hi[i] * inh; }

    float ps = 0.f;
    // shifts s = 1,3,5,7 : dot(Ln, roll(Ln, s)); rolled[f] = Ln[(f-s) mod 8]
    #pragma unroll
    for (int s = 1; s < FILTER_LEN; s += 2) {
        float d = 0.f;
        #pragma unroll
        for (int f = 0; f < 8; ++f) d += Ln[f] * Ln[(f - s) & 7];
        ps += fabsf(d);
    }
    float dlh = 0.f, dll = 0.f, dhh = 0.f;
    #pragma unroll
    for (int f = 0; f < 8; ++f) {
        dlh += Ln[f] * Hn[f];
        dll += Ln[f] * Ln[f];
        dhh += Hn[f] * Hn[f];
    }
    ps += fabsf(dlh) + fabsf(dll - 1.f) + fabsf(dhh - 1.f);

    // block reduce (256 threads = 4 waves)
    #pragma unroll
    for (int off = 32; off > 0; off >>= 1) ps += __shfl_down(ps, off, 64);
    __shared__ float sred[4];
    if ((b & 63) == 0) sred[b >> 6] = ps;
    __syncthreads();
    if (b == 0) {
        float total = sred[0] + sred[1] + sred[2] + sred[3];
        out[2 * BATCH * FILTER_LEN] = total * (1.0f / BATCH);
    }
}

extern "C" void kernel_launch(void* const* d_in, const int* in_sizes, int n_in,
                              void* d_out, int out_size, void* d_ws, size_t ws_size,
                              hipStream_t stream) {
    const float4* x  = (const float4*)d_in[0];
    const float* W1 = (const float*)d_in[1];
    const float* b1 = (const float*)d_in[2];
    const float* W2 = (const float*)d_in[3];
    const float* b2 = (const float*)d_in[4];
    const float* W3 = (const float*)d_in[5];
    const float* b3 = (const float*)d_in[6];
    float* out = (float*)d_out;

    float* stat = (float*)d_ws;                                                    // 131072 floats
    float* filt = (float*)((char*)d_ws + (size_t)BATCH * CHANNEL * sizeof(float)); // 4096 floats

    rowmax_kernel<<<(BATCH * CHANNEL) / 4, 256, 0, stream>>>(x, stat);
    mlp_kernel<<<BATCH, 64, 0, stream>>>(stat, W1, b1, W2, b2, W3, b3, out, filt);
    loss_kernel<<<1, 256, 0, stream>>>(filt, out);
}